// Round 1
// baseline (1327.456 us; speedup 1.0000x reference)
//
#include <hip/hip_runtime.h>

typedef unsigned short u16;
typedef __attribute__((ext_vector_type(8))) __bf16 bf16x8;
typedef __attribute__((ext_vector_type(4))) float f32x4;

#define SEQ 2048
#define DMODEL 2048
#define NHEADS 16
#define DHEAD 128
#define MTOT 8192  // B*T

typedef __attribute__((address_space(1))) void gvoid_t;
typedef __attribute__((address_space(3))) void lvoid_t;

__device__ inline void gload_lds16(const void* g, void* l) {
  __builtin_amdgcn_global_load_lds((gvoid_t*)g, (lvoid_t*)l, 16, 0, 0);
}

__device__ inline u16 f2bf(float f) {
  unsigned u = __float_as_uint(f);
  unsigned r = (u + 0x7fffu + ((u >> 16) & 1u)) >> 16;
  return (u16)r;
}

__global__ __launch_bounds__(256) void cvt_f32_bf16(const float* __restrict__ in,
                                                    u16* __restrict__ out, int n4) {
  int i = blockIdx.x * 256 + threadIdx.x;
  if (i >= n4) return;
  float4 v = reinterpret_cast<const float4*>(in)[i];
  ushort4 o;
  o.x = f2bf(v.x); o.y = f2bf(v.y); o.z = f2bf(v.z); o.w = f2bf(v.w);
  reinterpret_cast<ushort4*>(out)[i] = o;
}

// C[m,n] = sum_k A[m,k]*B[n,k]  (both row-major over k; "B^T" GEMM)
// MODE 0: QKV epilogue (+bias, scatter to Q(scaled)/K/V^T bf16 buffers)
// MODE 1: fp32 out = acc + bias
template <int MODE>
__global__ __launch_bounds__(256) void gemm_bt(
    const u16* __restrict__ A, const u16* __restrict__ B,
    const float* __restrict__ bias, int M, int N, int K,
    u16* __restrict__ qb, u16* __restrict__ kb, u16* __restrict__ vtb,
    float* __restrict__ outf) {
  __shared__ __align__(16) u16 As[128 * 32];
  __shared__ __align__(16) u16 Bs[128 * 32];
  const int tid = threadIdx.x;
  const int lane = tid & 63;
  const int w = tid >> 6;
  const int wr = w >> 1, wc = w & 1;
  const int m0 = blockIdx.x * 128, n0 = blockIdx.y * 128;

  f32x4 acc[4][4];
#pragma unroll
  for (int m = 0; m < 4; m++)
#pragma unroll
    for (int n = 0; n < 4; n++) acc[m][n] = f32x4{0.f, 0.f, 0.f, 0.f};

  const int srow = lane >> 2;        // 0..15
  const int scol = (lane & 3) * 8;   // 0,8,16,24 (elements)
  const int fr = lane & 15;
  const int kr = (lane >> 4) * 8;

  for (int kt = 0; kt < K; kt += 32) {
#pragma unroll
    for (int i = 0; i < 2; i++) {
      int inst = w * 2 + i;
      int row = inst * 16 + srow;
      gload_lds16(A + (size_t)(m0 + row) * K + kt + scol, &As[inst * 512 + lane * 8]);
      gload_lds16(B + (size_t)(n0 + row) * K + kt + scol, &Bs[inst * 512 + lane * 8]);
    }
    __syncthreads();
    bf16x8 af[4], bfr[4];
#pragma unroll
    for (int m = 0; m < 4; m++) af[m] = *(const bf16x8*)&As[(wr * 64 + m * 16 + fr) * 32 + kr];
#pragma unroll
    for (int n = 0; n < 4; n++) bfr[n] = *(const bf16x8*)&Bs[(wc * 64 + n * 16 + fr) * 32 + kr];
#pragma unroll
    for (int m = 0; m < 4; m++)
#pragma unroll
      for (int n = 0; n < 4; n++)
        acc[m][n] = __builtin_amdgcn_mfma_f32_16x16x32_bf16(af[m], bfr[n], acc[m][n], 0, 0, 0);
    __syncthreads();
  }

  if (MODE == 0) {
    const int which = n0 >> 11;          // 0=Q 1=K 2=V
    const int h = (n0 & 2047) >> 7;      // head (tile spans exactly one head)
#pragma unroll
    for (int m = 0; m < 4; m++) {
      const int trow = m0 + wr * 64 + m * 16 + ((lane >> 4) * 4);
      const int b = trow >> 11;
      const int t = trow & 2047;
#pragma unroll
      for (int n = 0; n < 4; n++) {
        const int dh = wc * 64 + n * 16 + fr;
        const float bv = bias[n0 + dh];
        if (which == 2) {
          ushort4 pk;
          pk.x = f2bf(acc[m][n][0] + bv);
          pk.y = f2bf(acc[m][n][1] + bv);
          pk.z = f2bf(acc[m][n][2] + bv);
          pk.w = f2bf(acc[m][n][3] + bv);
          *reinterpret_cast<ushort4*>(vtb + ((size_t)(b * NHEADS + h) * DHEAD + dh) * SEQ + t) = pk;
        } else {
          u16* dst = (which == 0) ? qb : kb;
          const float sc = (which == 0) ? 0.08838834764831845f : 1.0f;
#pragma unroll
          for (int r = 0; r < 4; r++)
            dst[((size_t)(b * NHEADS + h) * SEQ + (t + r)) * DHEAD + dh] =
                f2bf((acc[m][n][r] + bv) * sc);
        }
      }
    }
  } else {
#pragma unroll
    for (int m = 0; m < 4; m++) {
      const int row = m0 + wr * 64 + m * 16 + ((lane >> 4) * 4);
#pragma unroll
      for (int n = 0; n < 4; n++) {
        const int col = n0 + wc * 64 + n * 16 + fr;
        const float bv = bias[col];
#pragma unroll
        for (int r = 0; r < 4; r++) outf[(size_t)(row + r) * N + col] = acc[m][n][r] + bv;
      }
    }
  }
}

// Flash attention, non-causal. Q pre-scaled. Grid: (SEQ/64, B*H). 4 waves, wave
// owns 16 Q rows x 128 dh. K layout (bh,t,dh); V stored transposed (bh,dh,t).
__global__ __launch_bounds__(256) void attn_fwd(const u16* __restrict__ Q,
                                                const u16* __restrict__ Kb,
                                                const u16* __restrict__ VT,
                                                u16* __restrict__ O) {
  __shared__ __align__(16) u16 P_lds[4][16][72];  // +8 pad: 2-way-conflict-free b128 reads
  const int bh = blockIdx.y;
  const int b = bh >> 4, h = bh & 15;
  const int w = threadIdx.x >> 6;
  const int lane = threadIdx.x & 63;
  const int q0 = blockIdx.x * 64 + w * 16;
  const int fr = lane & 15;
  const int kr = (lane >> 4) * 8;
  const int g4 = (lane >> 4) * 4;

  const u16* Qp = Q + (size_t)bh * SEQ * DHEAD;
  const u16* Kp = Kb + (size_t)bh * SEQ * DHEAD;
  const u16* Vp = VT + (size_t)bh * DHEAD * SEQ;

  bf16x8 qf[4];
#pragma unroll
  for (int kk = 0; kk < 4; kk++)
    qf[kk] = *(const bf16x8*)(Qp + (size_t)(q0 + fr) * DHEAD + kk * 32 + kr);

  f32x4 oacc[8];
#pragma unroll
  for (int i = 0; i < 8; i++) oacc[i] = f32x4{0.f, 0.f, 0.f, 0.f};
  float mrun[4] = {-1e30f, -1e30f, -1e30f, -1e30f};
  float lrun[4] = {0.f, 0.f, 0.f, 0.f};

  for (int kv0 = 0; kv0 < SEQ; kv0 += 64) {
    f32x4 s[4];
#pragma unroll
    for (int ct = 0; ct < 4; ct++) {
      f32x4 sa = f32x4{0.f, 0.f, 0.f, 0.f};
      const u16* kp = Kp + (size_t)(kv0 + ct * 16 + fr) * DHEAD + kr;
#pragma unroll
      for (int kk = 0; kk < 4; kk++) {
        bf16x8 kf = *(const bf16x8*)(kp + kk * 32);
        sa = __builtin_amdgcn_mfma_f32_16x16x32_bf16(qf[kk], kf, sa, 0, 0, 0);
      }
      s[ct] = sa;
    }
    float sf[4];
#pragma unroll
    for (int r = 0; r < 4; r++) {
      float mx = fmaxf(fmaxf(s[0][r], s[1][r]), fmaxf(s[2][r], s[3][r]));
#pragma unroll
      for (int d = 1; d < 16; d <<= 1) mx = fmaxf(mx, __shfl_xor(mx, d, 64));
      float nm = fmaxf(mrun[r], mx);
      sf[r] = __expf(mrun[r] - nm);
      mrun[r] = nm;
    }
#pragma unroll
    for (int ct = 0; ct < 4; ct++)
#pragma unroll
      for (int r = 0; r < 4; r++) s[ct][r] = __expf(s[ct][r] - mrun[r]);
#pragma unroll
    for (int r = 0; r < 4; r++) {
      float su = s[0][r] + s[1][r] + s[2][r] + s[3][r];
#pragma unroll
      for (int d = 1; d < 16; d <<= 1) su += __shfl_xor(su, d, 64);
      lrun[r] = lrun[r] * sf[r] + su;
    }
#pragma unroll
    for (int dt = 0; dt < 8; dt++) {
      oacc[dt][0] *= sf[0]; oacc[dt][1] *= sf[1];
      oacc[dt][2] *= sf[2]; oacc[dt][3] *= sf[3];
    }
#pragma unroll
    for (int ct = 0; ct < 4; ct++)
#pragma unroll
      for (int r = 0; r < 4; r++) P_lds[w][g4 + r][ct * 16 + fr] = f2bf(s[ct][r]);
    bf16x8 pf[2];
#pragma unroll
    for (int kk = 0; kk < 2; kk++) pf[kk] = *(const bf16x8*)&P_lds[w][fr][kk * 32 + kr];
#pragma unroll
    for (int dt = 0; dt < 8; dt++) {
      const u16* vp = Vp + (size_t)(dt * 16 + fr) * SEQ + kv0 + kr;
#pragma unroll
      for (int kk = 0; kk < 2; kk++) {
        bf16x8 vf = *(const bf16x8*)(vp + kk * 32);
        oacc[dt] = __builtin_amdgcn_mfma_f32_16x16x32_bf16(pf[kk], vf, oacc[dt], 0, 0, 0);
      }
    }
  }
#pragma unroll
  for (int r = 0; r < 4; r++) {
    float inv = 1.0f / lrun[r];
    const int t = q0 + g4 + r;
    u16* op = O + ((size_t)(b * SEQ + t)) * DMODEL + h * DHEAD;
#pragma unroll
    for (int dt = 0; dt < 8; dt++) op[dt * 16 + fr] = f2bf(oacc[dt][r] * inv);
  }
}

extern "C" void kernel_launch(void* const* d_in, const int* in_sizes, int n_in,
                              void* d_out, int out_size, void* d_ws, size_t ws_size,
                              hipStream_t stream) {
  const float* x = (const float*)d_in[0];
  const float* qkv_w = (const float*)d_in[1];
  const float* qkv_b = (const float*)d_in[2];
  const float* out_w = (const float*)d_in[3];
  const float* out_b = (const float*)d_in[4];
  float* out = (float*)d_out;

  char* ws = (char*)d_ws;
  u16* xb = (u16*)ws;                                   // 8192x2048 bf16 (33.5MB)
  u16* wqkv = (u16*)(ws + 33554432);                    // 6144x2048 bf16 (25.2MB)
  u16* qb = (u16*)(ws + 33554432 + 25165824);           // 64x2048x128 each
  u16* kb = qb + (size_t)64 * SEQ * DHEAD;
  u16* vtb = kb + (size_t)64 * SEQ * DHEAD;
  u16* attnb = xb;   // alias: x consumed by GEMM1 before attention writes
  u16* outwb = wqkv; // alias: qkv_w consumed by GEMM1 before this convert

  cvt_f32_bf16<<<16777216 / 4 / 256, 256, 0, stream>>>(x, xb, 16777216 / 4);
  cvt_f32_bf16<<<12582912 / 4 / 256, 256, 0, stream>>>(qkv_w, wqkv, 12582912 / 4);
  dim3 g1(8192 / 128, 6144 / 128);
  gemm_bt<0><<<g1, 256, 0, stream>>>(xb, wqkv, qkv_b, 8192, 6144, 2048, qb, kb, vtb, nullptr);
  cvt_f32_bf16<<<4194304 / 4 / 256, 256, 0, stream>>>(out_w, outwb, 4194304 / 4);
  dim3 ga(SEQ / 64, 64);
  attn_fwd<<<ga, 256, 0, stream>>>(qb, kb, vtb, attnb);
  dim3 g2(8192 / 128, 2048 / 128);
  gemm_bt<1><<<g2, 256, 0, stream>>>(attnb, outwb, out_b, 8192, 2048, 2048, nullptr, nullptr,
                                     nullptr, out);
}

// Round 2
// 700.150 us; speedup vs baseline: 1.8960x; 1.8960x over previous
//
#include <hip/hip_runtime.h>

typedef unsigned short u16;
typedef __attribute__((ext_vector_type(8))) __bf16 bf16x8;
typedef __attribute__((ext_vector_type(4))) float f32x4;

#define SEQ 2048
#define DMODEL 2048
#define NHEADS 16
#define DHEAD 128
#define MTOT 8192  // B*T

typedef __attribute__((address_space(1))) void gvoid_t;
typedef __attribute__((address_space(3))) void lvoid_t;

__device__ inline void gload_lds16(const void* g, void* l) {
  __builtin_amdgcn_global_load_lds((gvoid_t*)g, (lvoid_t*)l, 16, 0, 0);
}

__device__ inline u16 f2bf(float f) {
  unsigned u = __float_as_uint(f);
  unsigned r = (u + 0x7fffu + ((u >> 16) & 1u)) >> 16;
  return (u16)r;
}

__global__ __launch_bounds__(256) void cvt_f32_bf16(const float* __restrict__ in,
                                                    u16* __restrict__ out, int n4) {
  int i = blockIdx.x * 256 + threadIdx.x;
  if (i >= n4) return;
  float4 v = reinterpret_cast<const float4*>(in)[i];
  ushort4 o;
  o.x = f2bf(v.x); o.y = f2bf(v.y); o.z = f2bf(v.z); o.w = f2bf(v.w);
  reinterpret_cast<ushort4*>(out)[i] = o;
}

// C[m,n] = sum_k A[m,k]*B[n,k]  (both row-major over k; "B^T" GEMM)
// MODE 0: QKV epilogue (+bias, scatter to Q(scaled)/K/V^T bf16 buffers)
// MODE 1: fp32 out = acc + bias
template <int MODE>
__global__ __launch_bounds__(256) void gemm_bt(
    const u16* __restrict__ A, const u16* __restrict__ B,
    const float* __restrict__ bias, int M, int N, int K,
    u16* __restrict__ qb, u16* __restrict__ kb, u16* __restrict__ vtb,
    float* __restrict__ outf) {
  __shared__ __align__(16) u16 As[128 * 32];
  __shared__ __align__(16) u16 Bs[128 * 32];
  const int tid = threadIdx.x;
  const int lane = tid & 63;
  const int w = tid >> 6;
  const int wr = w >> 1, wc = w & 1;
  const int m0 = blockIdx.x * 128, n0 = blockIdx.y * 128;

  f32x4 acc[4][4];
#pragma unroll
  for (int m = 0; m < 4; m++)
#pragma unroll
    for (int n = 0; n < 4; n++) acc[m][n] = f32x4{0.f, 0.f, 0.f, 0.f};

  const int srow = lane >> 2;        // 0..15
  const int scol = (lane & 3) * 8;   // 0,8,16,24 (elements)
  const int fr = lane & 15;
  const int kr = (lane >> 4) * 8;

  for (int kt = 0; kt < K; kt += 32) {
#pragma unroll
    for (int i = 0; i < 2; i++) {
      int inst = w * 2 + i;
      int row = inst * 16 + srow;
      gload_lds16(A + (size_t)(m0 + row) * K + kt + scol, &As[inst * 512 + lane * 8]);
      gload_lds16(B + (size_t)(n0 + row) * K + kt + scol, &Bs[inst * 512 + lane * 8]);
    }
    __syncthreads();
    bf16x8 af[4], bfr[4];
#pragma unroll
    for (int m = 0; m < 4; m++) af[m] = *(const bf16x8*)&As[(wr * 64 + m * 16 + fr) * 32 + kr];
#pragma unroll
    for (int n = 0; n < 4; n++) bfr[n] = *(const bf16x8*)&Bs[(wc * 64 + n * 16 + fr) * 32 + kr];
#pragma unroll
    for (int m = 0; m < 4; m++)
#pragma unroll
      for (int n = 0; n < 4; n++)
        acc[m][n] = __builtin_amdgcn_mfma_f32_16x16x32_bf16(af[m], bfr[n], acc[m][n], 0, 0, 0);
    __syncthreads();
  }

  if (MODE == 0) {
    const int which = n0 >> 11;          // 0=Q 1=K 2=V
    const int h = (n0 & 2047) >> 7;      // head (tile spans exactly one head)
#pragma unroll
    for (int m = 0; m < 4; m++) {
      const int trow = m0 + wr * 64 + m * 16 + ((lane >> 4) * 4);
      const int b = trow >> 11;
      const int t = trow & 2047;
#pragma unroll
      for (int n = 0; n < 4; n++) {
        const int dh = wc * 64 + n * 16 + fr;
        const float bv = bias[n0 + dh];
        if (which == 2) {
          ushort4 pk;
          pk.x = f2bf(acc[m][n][0] + bv);
          pk.y = f2bf(acc[m][n][1] + bv);
          pk.z = f2bf(acc[m][n][2] + bv);
          pk.w = f2bf(acc[m][n][3] + bv);
          *reinterpret_cast<ushort4*>(vtb + ((size_t)(b * NHEADS + h) * DHEAD + dh) * SEQ + t) = pk;
        } else {
          u16* dst = (which == 0) ? qb : kb;
          const float sc = (which == 0) ? 0.08838834764831845f : 1.0f;
#pragma unroll
          for (int r = 0; r < 4; r++)
            dst[((size_t)(b * NHEADS + h) * SEQ + (t + r)) * DHEAD + dh] =
                f2bf((acc[m][n][r] + bv) * sc);
        }
      }
    }
  } else {
#pragma unroll
    for (int m = 0; m < 4; m++) {
      const int row = m0 + wr * 64 + m * 16 + ((lane >> 4) * 4);
#pragma unroll
      for (int n = 0; n < 4; n++) {
        const int col = n0 + wc * 64 + n * 16 + fr;
        const float bv = bias[col];
#pragma unroll
        for (int r = 0; r < 4; r++) outf[(size_t)(row + r) * N + col] = acc[m][n][r] + bv;
      }
    }
  }
}

// Flash attention, non-causal. Q pre-scaled. Grid: (SEQ/128, B*H). 4 waves,
// each wave owns 32 Q rows x 128 dh. K tile (64x128) and V^T tile (128x64)
// staged in XOR-swizzled LDS, shared by all 4 waves, reg-staged prefetch
// (T14: issue next tile's loads before compute so latency hides under MFMA).
__global__ __launch_bounds__(256, 2) void attn_fwd(const u16* __restrict__ Q,
                                                   const u16* __restrict__ Kb,
                                                   const u16* __restrict__ VT,
                                                   u16* __restrict__ O) {
  __shared__ __align__(16) u16 Ks[64 * 128];       // swizzled: 16B unit c16 ^= row&7
  __shared__ __align__(16) u16 Vs[128 * 64];       // swizzled: 16B unit c8  ^= row&7
  __shared__ __align__(16) u16 P_lds[4][32][72];   // +8 pad: 2-way conflicts only
  const int bh = blockIdx.y;
  const int b = bh >> 4, h = bh & 15;
  const int w = threadIdx.x >> 6;
  const int lane = threadIdx.x & 63;
  const int fr = lane & 15;
  const int hi = lane >> 4;
  const int kr = hi * 8;
  const int g4 = hi * 4;
  const int q0w = blockIdx.x * 128 + w * 32;

  const u16* Qp = Q + (size_t)bh * SEQ * DHEAD;
  const u16* Kp = Kb + (size_t)bh * SEQ * DHEAD;
  const u16* Vp = VT + (size_t)bh * DHEAD * SEQ;

  // Q resident in registers for the whole kernel (32 rows x 128 per wave).
  bf16x8 qf[2][4];
#pragma unroll
  for (int mg = 0; mg < 2; mg++)
#pragma unroll
    for (int kk = 0; kk < 4; kk++)
      qf[mg][kk] = *(const bf16x8*)(Qp + (size_t)(q0w + mg * 16 + fr) * DHEAD + kk * 32 + kr);

  f32x4 oacc[2][8];
#pragma unroll
  for (int mg = 0; mg < 2; mg++)
#pragma unroll
    for (int i = 0; i < 8; i++) oacc[mg][i] = f32x4{0.f, 0.f, 0.f, 0.f};
  float mrun[2][4] = {{-1e30f, -1e30f, -1e30f, -1e30f}, {-1e30f, -1e30f, -1e30f, -1e30f}};
  float lrun[2][4] = {{0.f, 0.f, 0.f, 0.f}, {0.f, 0.f, 0.f, 0.f}};

  bf16x8 kreg[4], vreg[4];
  // prologue: load tile 0 into regs
#pragma unroll
  for (int i = 0; i < 4; i++) {
    const int u = w * 256 + i * 64 + lane;
    const int rK = u >> 4, c16 = u & 15;
    kreg[i] = *(const bf16x8*)(Kp + (size_t)rK * DHEAD + c16 * 8);
    const int rV = u >> 3, c8 = u & 7;
    vreg[i] = *(const bf16x8*)(Vp + (size_t)rV * SEQ + c8 * 8);
  }

  for (int kv0 = 0; kv0 < SEQ; kv0 += 64) {
    __syncthreads();  // previous tile fully consumed by all waves
    // write staged regs -> swizzled LDS
#pragma unroll
    for (int i = 0; i < 4; i++) {
      const int u = w * 256 + i * 64 + lane;
      const int rK = u >> 4, c16 = u & 15;
      *(bf16x8*)&Ks[rK * 128 + ((c16 ^ (rK & 7)) * 8)] = kreg[i];
      const int rV = u >> 3, c8 = u & 7;
      *(bf16x8*)&Vs[rV * 64 + ((c8 ^ (rV & 7)) * 8)] = vreg[i];
    }
    __syncthreads();  // tile visible to all waves
    // issue next tile's global loads now; latency hides under compute below
    if (kv0 + 64 < SEQ) {
      const int kvn = kv0 + 64;
#pragma unroll
      for (int i = 0; i < 4; i++) {
        const int u = w * 256 + i * 64 + lane;
        const int rK = u >> 4, c16 = u & 15;
        kreg[i] = *(const bf16x8*)(Kp + (size_t)(kvn + rK) * DHEAD + c16 * 8);
        const int rV = u >> 3, c8 = u & 7;
        vreg[i] = *(const bf16x8*)(Vp + (size_t)rV * SEQ + kvn + c8 * 8);
      }
    }

    // QK^T: s[mg][ct], K fragments shared across both row groups
    f32x4 s[2][4];
#pragma unroll
    for (int mg = 0; mg < 2; mg++)
#pragma unroll
      for (int ct = 0; ct < 4; ct++) s[mg][ct] = f32x4{0.f, 0.f, 0.f, 0.f};
#pragma unroll
    for (int ct = 0; ct < 4; ct++) {
      const int row = ct * 16 + fr;
#pragma unroll
      for (int kk = 0; kk < 4; kk++) {
        bf16x8 kf = *(const bf16x8*)&Ks[row * 128 + (((kk * 4 + hi) ^ (row & 7)) * 8)];
        s[0][ct] = __builtin_amdgcn_mfma_f32_16x16x32_bf16(qf[0][kk], kf, s[0][ct], 0, 0, 0);
        s[1][ct] = __builtin_amdgcn_mfma_f32_16x16x32_bf16(qf[1][kk], kf, s[1][ct], 0, 0, 0);
      }
    }

    // online softmax per row group; P -> LDS (bf16)
    float sf[2][4];
#pragma unroll
    for (int mg = 0; mg < 2; mg++) {
#pragma unroll
      for (int r = 0; r < 4; r++) {
        float mx = fmaxf(fmaxf(s[mg][0][r], s[mg][1][r]), fmaxf(s[mg][2][r], s[mg][3][r]));
#pragma unroll
        for (int d = 1; d < 16; d <<= 1) mx = fmaxf(mx, __shfl_xor(mx, d, 64));
        float nm = fmaxf(mrun[mg][r], mx);
        sf[mg][r] = __expf(mrun[mg][r] - nm);
        mrun[mg][r] = nm;
      }
#pragma unroll
      for (int ct = 0; ct < 4; ct++)
#pragma unroll
        for (int r = 0; r < 4; r++) s[mg][ct][r] = __expf(s[mg][ct][r] - mrun[mg][r]);
#pragma unroll
      for (int r = 0; r < 4; r++) {
        float su = s[mg][0][r] + s[mg][1][r] + s[mg][2][r] + s[mg][3][r];
#pragma unroll
        for (int d = 1; d < 16; d <<= 1) su += __shfl_xor(su, d, 64);
        lrun[mg][r] = lrun[mg][r] * sf[mg][r] + su;
      }
#pragma unroll
      for (int dt = 0; dt < 8; dt++) {
        oacc[mg][dt][0] *= sf[mg][0]; oacc[mg][dt][1] *= sf[mg][1];
        oacc[mg][dt][2] *= sf[mg][2]; oacc[mg][dt][3] *= sf[mg][3];
      }
#pragma unroll
      for (int ct = 0; ct < 4; ct++)
#pragma unroll
        for (int r = 0; r < 4; r++)
          P_lds[w][mg * 16 + g4 + r][ct * 16 + fr] = f2bf(s[mg][ct][r]);
    }

    // PV: V fragments shared across both row groups
    bf16x8 pf[2][2];
#pragma unroll
    for (int mg = 0; mg < 2; mg++)
#pragma unroll
      for (int kk = 0; kk < 2; kk++)
        pf[mg][kk] = *(const bf16x8*)&P_lds[w][mg * 16 + fr][kk * 32 + kr];
#pragma unroll
    for (int dt = 0; dt < 8; dt++) {
      const int row = dt * 16 + fr;
#pragma unroll
      for (int kk = 0; kk < 2; kk++) {
        bf16x8 vf = *(const bf16x8*)&Vs[row * 64 + (((kk * 4 + hi) ^ (row & 7)) * 8)];
        oacc[0][dt] = __builtin_amdgcn_mfma_f32_16x16x32_bf16(pf[0][kk], vf, oacc[0][dt], 0, 0, 0);
        oacc[1][dt] = __builtin_amdgcn_mfma_f32_16x16x32_bf16(pf[1][kk], vf, oacc[1][dt], 0, 0, 0);
      }
    }
  }

#pragma unroll
  for (int mg = 0; mg < 2; mg++)
#pragma unroll
    for (int r = 0; r < 4; r++) {
      float inv = 1.0f / lrun[mg][r];
      const int t = q0w + mg * 16 + g4 + r;
      u16* op = O + ((size_t)(b * SEQ + t)) * DMODEL + h * DHEAD;
#pragma unroll
      for (int dt = 0; dt < 8; dt++) op[dt * 16 + fr] = f2bf(oacc[mg][dt][r] * inv);
    }
}

extern "C" void kernel_launch(void* const* d_in, const int* in_sizes, int n_in,
                              void* d_out, int out_size, void* d_ws, size_t ws_size,
                              hipStream_t stream) {
  const float* x = (const float*)d_in[0];
  const float* qkv_w = (const float*)d_in[1];
  const float* qkv_b = (const float*)d_in[2];
  const float* out_w = (const float*)d_in[3];
  const float* out_b = (const float*)d_in[4];
  float* out = (float*)d_out;

  char* ws = (char*)d_ws;
  u16* xb = (u16*)ws;                                   // 8192x2048 bf16 (33.5MB)
  u16* wqkv = (u16*)(ws + 33554432);                    // 6144x2048 bf16 (25.2MB)
  u16* qb = (u16*)(ws + 33554432 + 25165824);           // 64x2048x128 each
  u16* kb = qb + (size_t)64 * SEQ * DHEAD;
  u16* vtb = kb + (size_t)64 * SEQ * DHEAD;
  u16* attnb = xb;   // alias: x consumed by GEMM1 before attention writes
  u16* outwb = wqkv; // alias: qkv_w consumed by GEMM1 before this convert

  cvt_f32_bf16<<<16777216 / 4 / 256, 256, 0, stream>>>(x, xb, 16777216 / 4);
  cvt_f32_bf16<<<12582912 / 4 / 256, 256, 0, stream>>>(qkv_w, wqkv, 12582912 / 4);
  dim3 g1(8192 / 128, 6144 / 128);
  gemm_bt<0><<<g1, 256, 0, stream>>>(xb, wqkv, qkv_b, 8192, 6144, 2048, qb, kb, vtb, nullptr);
  cvt_f32_bf16<<<4194304 / 4 / 256, 256, 0, stream>>>(out_w, outwb, 4194304 / 4);
  dim3 ga(SEQ / 128, 64);
  attn_fwd<<<ga, 256, 0, stream>>>(qb, kb, vtb, attnb);
  dim3 g2(8192 / 128, 2048 / 128);
  gemm_bt<1><<<g2, 256, 0, stream>>>(attnb, outwb, out_b, 8192, 2048, 2048, nullptr, nullptr,
                                     nullptr, out);
}

// Round 3
// 570.456 us; speedup vs baseline: 2.3270x; 1.2274x over previous
//
#include <hip/hip_runtime.h>

typedef unsigned short u16;
typedef __attribute__((ext_vector_type(8))) __bf16 bf16x8;
typedef __attribute__((ext_vector_type(4))) float f32x4;

#define SEQ 2048
#define DMODEL 2048
#define NHEADS 16
#define DHEAD 128

typedef __attribute__((address_space(1))) void gvoid_t;
typedef __attribute__((address_space(3))) void lvoid_t;

__device__ inline void gload_lds16(const void* g, void* l) {
  __builtin_amdgcn_global_load_lds((gvoid_t*)g, (lvoid_t*)l, 16, 0, 0);
}

__device__ inline u16 f2bf(float f) {
  unsigned u = __float_as_uint(f);
  unsigned r = (u + 0x7fffu + ((u >> 16) & 1u)) >> 16;
  return (u16)r;
}

__global__ __launch_bounds__(256) void cvt_f32_bf16(const float* __restrict__ in,
                                                    u16* __restrict__ out, int n4) {
  int i = blockIdx.x * 256 + threadIdx.x;
  if (i >= n4) return;
  float4 v = reinterpret_cast<const float4*>(in)[i];
  ushort4 o;
  o.x = f2bf(v.x); o.y = f2bf(v.y); o.z = f2bf(v.z); o.w = f2bf(v.w);
  reinterpret_cast<ushort4*>(out)[i] = o;
}

// ---------------- 256x256 8-phase GEMM (T1+T2+T3+T4+T5) ----------------
// C[m,n] = sum_k A[m,k]*B[n,k]. 512 thr = 8 waves (2M x 4N), BK=64, LDS 128KB
// double-buffered, XOR-swizzled (16B-unit ^= row&7) via pre-swizzled global
// source for global_load_lds. Counted vmcnt(8), raw barriers, setprio on MFMA.
// MODE 0: QKV epilogue (+bias, scatter to Q(scaled)/K/V^T bf16). MODE 1: fp32.

#define GBAR() __builtin_amdgcn_s_barrier()
#define LGKM0() do { asm volatile("s_waitcnt lgkmcnt(0)" ::: "memory"); \
                     __builtin_amdgcn_sched_barrier(0); } while (0)

template <int MODE>
__global__ __launch_bounds__(512, 1) void gemm256(
    const u16* __restrict__ A, const u16* __restrict__ B,
    const float* __restrict__ bias, int M, int N, int K, int nby,
    u16* __restrict__ qb, u16* __restrict__ kb, u16* __restrict__ vtb,
    float* __restrict__ outf) {
  __shared__ __align__(16) u16 As[2][256 * 64];
  __shared__ __align__(16) u16 Bs[2][256 * 64];
  const int nwg = gridDim.x;
  const int cpx = nwg >> 3;
  const int bid = blockIdx.x;
  const int sw = (bid & 7) * cpx + (bid >> 3);  // bijective: nwg % 8 == 0
  const int bx = sw / nby, by = sw % nby;
  const int m0 = bx * 256, n0 = by * 256;
  const int tid = threadIdx.x, lane = tid & 63, w = tid >> 6;
  const int wm = w >> 2, wn = w & 3;
  const int fr = lane & 15, hi = lane >> 4;
  const int g4 = hi * 4;
  const u16* Abase = A + (size_t)m0 * K;
  const u16* Bbase = B + (size_t)n0 * K;

  f32x4 acc[8][4];
#pragma unroll
  for (int i = 0; i < 8; i++)
#pragma unroll
    for (int j = 0; j < 4; j++) acc[i][j] = f32x4{0.f, 0.f, 0.f, 0.f};

// stage tile t into buffer p: 8 gloads/thread (4 A + 4 B), linear LDS dest,
// swizzled global src: LDS(r,u) <- global(r, u^(r&7))
#define STAGE(T, P)                                                              \
  do {                                                                           \
    const int t64 = (T) * 64;                                                    \
    _Pragma("unroll") for (int j = 0; j < 4; j++) {                              \
      const int U = (j * 8 + w) * 64 + lane;                                     \
      const int r_ = U >> 3;                                                     \
      const int us = (lane & 7) ^ (r_ & 7);                                      \
      gload_lds16(Abase + (size_t)r_ * K + t64 + us * 8, &As[P][U * 8]);         \
      gload_lds16(Bbase + (size_t)r_ * K + t64 + us * 8, &Bs[P][U * 8]);         \
    }                                                                            \
  } while (0)

#define LDA(AF, H, P)                                                            \
  do {                                                                           \
    _Pragma("unroll") for (int fi = 0; fi < 4; fi++) {                           \
      const int row = wm * 128 + (H) * 64 + fi * 16 + fr;                        \
      _Pragma("unroll") for (int kk = 0; kk < 2; kk++) {                         \
        const int u = (kk * 4 + hi) ^ (row & 7);                                 \
        AF[fi][kk] = *(const bf16x8*)&As[P][row * 64 + u * 8];                    \
      }                                                                          \
    }                                                                            \
  } while (0)

#define LDB(BF, G, P)                                                            \
  do {                                                                           \
    _Pragma("unroll") for (int fj = 0; fj < 2; fj++) {                           \
      const int row = wn * 64 + (G) * 32 + fj * 16 + fr;                         \
      _Pragma("unroll") for (int kk = 0; kk < 2; kk++) {                         \
        const int u = (kk * 4 + hi) ^ (row & 7);                                 \
        BF[fj][kk] = *(const bf16x8*)&Bs[P][row * 64 + u * 8];                    \
      }                                                                          \
    }                                                                            \
  } while (0)

#define MF(AF, BF, H, G)                                                         \
  do {                                                                           \
    __builtin_amdgcn_s_setprio(1);                                               \
    _Pragma("unroll") for (int fi = 0; fi < 4; fi++)                             \
    _Pragma("unroll") for (int fj = 0; fj < 2; fj++)                             \
    _Pragma("unroll") for (int kk = 0; kk < 2; kk++)                             \
      acc[(H) * 4 + fi][(G) * 2 + fj] = __builtin_amdgcn_mfma_f32_16x16x32_bf16( \
          AF[fi][kk], BF[fj][kk], acc[(H) * 4 + fi][(G) * 2 + fj], 0, 0, 0);     \
    __builtin_amdgcn_s_setprio(0);                                               \
  } while (0)

  const int NT = K >> 6;
  STAGE(0, 0);
  STAGE(1, 1);
  asm volatile("s_waitcnt vmcnt(8)" ::: "memory");
  __builtin_amdgcn_sched_barrier(0);
  GBAR();

  bf16x8 a[4][2], b0[2][2], b1[2][2];
  for (int t = 0; t < NT; t++) {
    const int p = t & 1;
    // ph0: A-half0 + B-half0, MFMA quadrant (0,0)
    LDA(a, 0, p);
    LDB(b0, 0, p);
    GBAR(); LGKM0();
    MF(a, b0, 0, 0);
    GBAR();
    // ph1: B-half1, quadrant (0,1)
    LDB(b1, 1, p);
    GBAR(); LGKM0();
    MF(a, b1, 0, 1);
    GBAR();
    // ph2: A-half1 (last read of buf p), quadrant (1,0)
    LDA(a, 1, p);
    GBAR(); LGKM0();
    MF(a, b0, 1, 0);
    GBAR();
    // ph3: stage tile t+2 into buf p; quadrant (1,1); counted vmcnt
    if (t + 2 < NT) STAGE(t + 2, p);
    GBAR();
    MF(a, b1, 1, 1);
    if (t + 2 < NT) {
      asm volatile("s_waitcnt vmcnt(8)" ::: "memory");
    } else if (t + 1 < NT) {
      asm volatile("s_waitcnt vmcnt(0)" ::: "memory");
    }
    __builtin_amdgcn_sched_barrier(0);
    GBAR();
  }

  // epilogue
  if (MODE == 0) {
    const int which = n0 >> 11;  // 0=Q 1=K 2=V (tile never straddles)
#pragma unroll
    for (int mi = 0; mi < 8; mi++) {
      const int trow = m0 + wm * 128 + mi * 16 + g4;
      const int b = trow >> 11;
      const int t = trow & 2047;
#pragma unroll
      for (int nj = 0; nj < 4; nj++) {
        const int col = n0 + wn * 64 + nj * 16 + fr;
        const int h = (col >> 7) & 15;
        const int dh = col & 127;
        const float bv = bias[col];
        if (which == 2) {
          ushort4 pk;
          pk.x = f2bf(acc[mi][nj][0] + bv);
          pk.y = f2bf(acc[mi][nj][1] + bv);
          pk.z = f2bf(acc[mi][nj][2] + bv);
          pk.w = f2bf(acc[mi][nj][3] + bv);
          *reinterpret_cast<ushort4*>(vtb + ((size_t)(b * NHEADS + h) * DHEAD + dh) * SEQ + t) = pk;
        } else {
          u16* dst = (which == 0) ? qb : kb;
          const float sc = (which == 0) ? 0.08838834764831845f : 1.0f;
#pragma unroll
          for (int r = 0; r < 4; r++)
            dst[((size_t)(b * NHEADS + h) * SEQ + (t + r)) * DHEAD + dh] =
                f2bf((acc[mi][nj][r] + bv) * sc);
        }
      }
    }
  } else {
#pragma unroll
    for (int mi = 0; mi < 8; mi++) {
      const int row = m0 + wm * 128 + mi * 16 + g4;
#pragma unroll
      for (int nj = 0; nj < 4; nj++) {
        const int col = n0 + wn * 64 + nj * 16 + fr;
        const float bv = bias[col];
#pragma unroll
        for (int r = 0; r < 4; r++) outf[(size_t)(row + r) * N + col] = acc[mi][nj][r] + bv;
      }
    }
  }
#undef STAGE
#undef LDA
#undef LDB
#undef MF
}

// Flash attention, non-causal. Q pre-scaled. Grid: (SEQ/128, B*H). 4 waves,
// each wave owns 32 Q rows x 128 dh. K tile (64x128) and V^T tile (128x64)
// staged in XOR-swizzled LDS, shared by all 4 waves, reg-staged prefetch.
__global__ __launch_bounds__(256, 2) void attn_fwd(const u16* __restrict__ Q,
                                                   const u16* __restrict__ Kb,
                                                   const u16* __restrict__ VT,
                                                   u16* __restrict__ O) {
  __shared__ __align__(16) u16 Ks[64 * 128];       // swizzled: 16B unit c16 ^= row&7
  __shared__ __align__(16) u16 Vs[128 * 64];       // swizzled: 16B unit c8  ^= row&7
  __shared__ __align__(16) u16 P_lds[4][32][72];   // +8 pad: 2-way conflicts only
  const int bh = blockIdx.y;
  const int b = bh >> 4, h = bh & 15;
  const int w = threadIdx.x >> 6;
  const int lane = threadIdx.x & 63;
  const int fr = lane & 15;
  const int hi = lane >> 4;
  const int kr = hi * 8;
  const int g4 = hi * 4;
  const int q0w = blockIdx.x * 128 + w * 32;

  const u16* Qp = Q + (size_t)bh * SEQ * DHEAD;
  const u16* Kp = Kb + (size_t)bh * SEQ * DHEAD;
  const u16* Vp = VT + (size_t)bh * DHEAD * SEQ;

  bf16x8 qf[2][4];
#pragma unroll
  for (int mg = 0; mg < 2; mg++)
#pragma unroll
    for (int kk = 0; kk < 4; kk++)
      qf[mg][kk] = *(const bf16x8*)(Qp + (size_t)(q0w + mg * 16 + fr) * DHEAD + kk * 32 + kr);

  f32x4 oacc[2][8];
#pragma unroll
  for (int mg = 0; mg < 2; mg++)
#pragma unroll
    for (int i = 0; i < 8; i++) oacc[mg][i] = f32x4{0.f, 0.f, 0.f, 0.f};
  float mrun[2][4] = {{-1e30f, -1e30f, -1e30f, -1e30f}, {-1e30f, -1e30f, -1e30f, -1e30f}};
  float lrun[2][4] = {{0.f, 0.f, 0.f, 0.f}, {0.f, 0.f, 0.f, 0.f}};

  bf16x8 kreg[4], vreg[4];
#pragma unroll
  for (int i = 0; i < 4; i++) {
    const int u = w * 256 + i * 64 + lane;
    const int rK = u >> 4, c16 = u & 15;
    kreg[i] = *(const bf16x8*)(Kp + (size_t)rK * DHEAD + c16 * 8);
    const int rV = u >> 3, c8 = u & 7;
    vreg[i] = *(const bf16x8*)(Vp + (size_t)rV * SEQ + c8 * 8);
  }

  for (int kv0 = 0; kv0 < SEQ; kv0 += 64) {
    __syncthreads();
#pragma unroll
    for (int i = 0; i < 4; i++) {
      const int u = w * 256 + i * 64 + lane;
      const int rK = u >> 4, c16 = u & 15;
      *(bf16x8*)&Ks[rK * 128 + ((c16 ^ (rK & 7)) * 8)] = kreg[i];
      const int rV = u >> 3, c8 = u & 7;
      *(bf16x8*)&Vs[rV * 64 + ((c8 ^ (rV & 7)) * 8)] = vreg[i];
    }
    __syncthreads();
    if (kv0 + 64 < SEQ) {
      const int kvn = kv0 + 64;
#pragma unroll
      for (int i = 0; i < 4; i++) {
        const int u = w * 256 + i * 64 + lane;
        const int rK = u >> 4, c16 = u & 15;
        kreg[i] = *(const bf16x8*)(Kp + (size_t)(kvn + rK) * DHEAD + c16 * 8);
        const int rV = u >> 3, c8 = u & 7;
        vreg[i] = *(const bf16x8*)(Vp + (size_t)rV * SEQ + kvn + c8 * 8);
      }
    }

    f32x4 s[2][4];
#pragma unroll
    for (int mg = 0; mg < 2; mg++)
#pragma unroll
      for (int ct = 0; ct < 4; ct++) s[mg][ct] = f32x4{0.f, 0.f, 0.f, 0.f};
    __builtin_amdgcn_s_setprio(1);
#pragma unroll
    for (int ct = 0; ct < 4; ct++) {
      const int row = ct * 16 + fr;
#pragma unroll
      for (int kk = 0; kk < 4; kk++) {
        bf16x8 kf = *(const bf16x8*)&Ks[row * 128 + (((kk * 4 + hi) ^ (row & 7)) * 8)];
        s[0][ct] = __builtin_amdgcn_mfma_f32_16x16x32_bf16(qf[0][kk], kf, s[0][ct], 0, 0, 0);
        s[1][ct] = __builtin_amdgcn_mfma_f32_16x16x32_bf16(qf[1][kk], kf, s[1][ct], 0, 0, 0);
      }
    }
    __builtin_amdgcn_s_setprio(0);

    float sf[2][4];
#pragma unroll
    for (int mg = 0; mg < 2; mg++) {
#pragma unroll
      for (int r = 0; r < 4; r++) {
        float mx = fmaxf(fmaxf(s[mg][0][r], s[mg][1][r]), fmaxf(s[mg][2][r], s[mg][3][r]));
#pragma unroll
        for (int d = 1; d < 16; d <<= 1) mx = fmaxf(mx, __shfl_xor(mx, d, 64));
        float nm = fmaxf(mrun[mg][r], mx);
        sf[mg][r] = __expf(mrun[mg][r] - nm);
        mrun[mg][r] = nm;
      }
#pragma unroll
      for (int ct = 0; ct < 4; ct++)
#pragma unroll
        for (int r = 0; r < 4; r++) s[mg][ct][r] = __expf(s[mg][ct][r] - mrun[mg][r]);
#pragma unroll
      for (int r = 0; r < 4; r++) {
        float su = s[mg][0][r] + s[mg][1][r] + s[mg][2][r] + s[mg][3][r];
#pragma unroll
        for (int d = 1; d < 16; d <<= 1) su += __shfl_xor(su, d, 64);
        lrun[mg][r] = lrun[mg][r] * sf[mg][r] + su;
      }
#pragma unroll
      for (int dt = 0; dt < 8; dt++) {
        oacc[mg][dt][0] *= sf[mg][0]; oacc[mg][dt][1] *= sf[mg][1];
        oacc[mg][dt][2] *= sf[mg][2]; oacc[mg][dt][3] *= sf[mg][3];
      }
#pragma unroll
      for (int ct = 0; ct < 4; ct++)
#pragma unroll
        for (int r = 0; r < 4; r++)
          P_lds[w][mg * 16 + g4 + r][ct * 16 + fr] = f2bf(s[mg][ct][r]);
    }

    bf16x8 pf[2][2];
#pragma unroll
    for (int mg = 0; mg < 2; mg++)
#pragma unroll
      for (int kk = 0; kk < 2; kk++)
        pf[mg][kk] = *(const bf16x8*)&P_lds[w][mg * 16 + fr][kk * 32 + kr];
    __builtin_amdgcn_s_setprio(1);
#pragma unroll
    for (int dt = 0; dt < 8; dt++) {
      const int row = dt * 16 + fr;
#pragma unroll
      for (int kk = 0; kk < 2; kk++) {
        bf16x8 vf = *(const bf16x8*)&Vs[row * 64 + (((kk * 4 + hi) ^ (row & 7)) * 8)];
        oacc[0][dt] = __builtin_amdgcn_mfma_f32_16x16x32_bf16(pf[0][kk], vf, oacc[0][dt], 0, 0, 0);
        oacc[1][dt] = __builtin_amdgcn_mfma_f32_16x16x32_bf16(pf[1][kk], vf, oacc[1][dt], 0, 0, 0);
      }
    }
    __builtin_amdgcn_s_setprio(0);
  }

#pragma unroll
  for (int mg = 0; mg < 2; mg++)
#pragma unroll
    for (int r = 0; r < 4; r++) {
      float inv = 1.0f / lrun[mg][r];
      const int t = q0w + mg * 16 + g4 + r;
      u16* op = O + ((size_t)(b * SEQ + t)) * DMODEL + h * DHEAD;
#pragma unroll
      for (int dt = 0; dt < 8; dt++) op[dt * 16 + fr] = f2bf(oacc[mg][dt][r] * inv);
    }
}

extern "C" void kernel_launch(void* const* d_in, const int* in_sizes, int n_in,
                              void* d_out, int out_size, void* d_ws, size_t ws_size,
                              hipStream_t stream) {
  const float* x = (const float*)d_in[0];
  const float* qkv_w = (const float*)d_in[1];
  const float* qkv_b = (const float*)d_in[2];
  const float* out_w = (const float*)d_in[3];
  const float* out_b = (const float*)d_in[4];
  float* out = (float*)d_out;

  char* ws = (char*)d_ws;
  u16* xb = (u16*)ws;                                   // 8192x2048 bf16 (33.5MB)
  u16* wqkv = (u16*)(ws + 33554432);                    // 6144x2048 bf16 (25.2MB)
  u16* qb = (u16*)(ws + 33554432 + 25165824);           // 64x2048x128 each
  u16* kb = qb + (size_t)64 * SEQ * DHEAD;
  u16* vtb = kb + (size_t)64 * SEQ * DHEAD;
  u16* attnb = xb;   // alias: x consumed by GEMM1 before attention writes
  u16* outwb = wqkv; // alias: qkv_w consumed by GEMM1 before this convert

  cvt_f32_bf16<<<16777216 / 4 / 256, 256, 0, stream>>>(x, xb, 16777216 / 4);
  cvt_f32_bf16<<<12582912 / 4 / 256, 256, 0, stream>>>(qkv_w, wqkv, 12582912 / 4);
  gemm256<0><<<768, 512, 0, stream>>>(xb, wqkv, qkv_b, 8192, 6144, 2048, 24, qb, kb, vtb,
                                      nullptr);
  cvt_f32_bf16<<<4194304 / 4 / 256, 256, 0, stream>>>(out_w, outwb, 4194304 / 4);
  dim3 ga(SEQ / 128, 64);
  attn_fwd<<<ga, 256, 0, stream>>>(qb, kb, vtb, attnb);
  gemm256<1><<<256, 512, 0, stream>>>(attnb, outwb, out_b, 8192, 2048, 2048, 8, nullptr,
                                      nullptr, nullptr, out);
}

// Round 4
// 500.342 us; speedup vs baseline: 2.6531x; 1.1401x over previous
//
#include <hip/hip_runtime.h>

typedef unsigned short u16;
typedef __attribute__((ext_vector_type(8))) __bf16 bf16x8;
typedef __attribute__((ext_vector_type(4))) float f32x4;

#define SEQ 2048
#define DMODEL 2048
#define NHEADS 16
#define DHEAD 128

typedef __attribute__((address_space(1))) void gvoid_t;
typedef __attribute__((address_space(3))) void lvoid_t;

__device__ inline void gload_lds16(const void* g, void* l) {
  __builtin_amdgcn_global_load_lds((gvoid_t*)g, (lvoid_t*)l, 16, 0, 0);
}

__device__ inline u16 f2bf(float f) {
  unsigned u = __float_as_uint(f);
  unsigned r = (u + 0x7fffu + ((u >> 16) & 1u)) >> 16;
  return (u16)r;
}

__global__ __launch_bounds__(256) void cvt_f32_bf16(const float* __restrict__ in,
                                                    u16* __restrict__ out, int n4) {
  int i = blockIdx.x * 256 + threadIdx.x;
  if (i >= n4) return;
  float4 v = reinterpret_cast<const float4*>(in)[i];
  ushort4 o;
  o.x = f2bf(v.x); o.y = f2bf(v.y); o.z = f2bf(v.z); o.w = f2bf(v.w);
  reinterpret_cast<ushort4*>(out)[i] = o;
}

// ---------------- 256x256 8-phase GEMM (T1+T2+T3+T4+T5) ----------------
#define GBAR() __builtin_amdgcn_s_barrier()
#define LGKM0() do { asm volatile("s_waitcnt lgkmcnt(0)" ::: "memory"); \
                     __builtin_amdgcn_sched_barrier(0); } while (0)

template <int MODE>
__global__ __launch_bounds__(512, 1) void gemm256(
    const u16* __restrict__ A, const u16* __restrict__ B,
    const float* __restrict__ bias, int M, int N, int K, int nby,
    u16* __restrict__ qb, u16* __restrict__ kb, u16* __restrict__ vtb,
    float* __restrict__ outf) {
  __shared__ __align__(16) u16 As[2][256 * 64];
  __shared__ __align__(16) u16 Bs[2][256 * 64];
  const int nwg = gridDim.x;
  const int cpx = nwg >> 3;
  const int bid = blockIdx.x;
  const int sw = (bid & 7) * cpx + (bid >> 3);  // bijective: nwg % 8 == 0
  const int bx = sw / nby, by = sw % nby;
  const int m0 = bx * 256, n0 = by * 256;
  const int tid = threadIdx.x, lane = tid & 63, w = tid >> 6;
  const int wm = w >> 2, wn = w & 3;
  const int fr = lane & 15, hi = lane >> 4;
  const int g4 = hi * 4;
  const u16* Abase = A + (size_t)m0 * K;
  const u16* Bbase = B + (size_t)n0 * K;

  f32x4 acc[8][4];
#pragma unroll
  for (int i = 0; i < 8; i++)
#pragma unroll
    for (int j = 0; j < 4; j++) acc[i][j] = f32x4{0.f, 0.f, 0.f, 0.f};

#define STAGE(T, P)                                                              \
  do {                                                                           \
    const int t64 = (T) * 64;                                                    \
    _Pragma("unroll") for (int j = 0; j < 4; j++) {                              \
      const int U = (j * 8 + w) * 64 + lane;                                     \
      const int r_ = U >> 3;                                                     \
      const int us = (lane & 7) ^ (r_ & 7);                                      \
      gload_lds16(Abase + (size_t)r_ * K + t64 + us * 8, &As[P][U * 8]);         \
      gload_lds16(Bbase + (size_t)r_ * K + t64 + us * 8, &Bs[P][U * 8]);         \
    }                                                                            \
  } while (0)

#define LDA(AF, H, P)                                                            \
  do {                                                                           \
    _Pragma("unroll") for (int fi = 0; fi < 4; fi++) {                           \
      const int row = wm * 128 + (H) * 64 + fi * 16 + fr;                        \
      _Pragma("unroll") for (int kk = 0; kk < 2; kk++) {                         \
        const int u = (kk * 4 + hi) ^ (row & 7);                                 \
        AF[fi][kk] = *(const bf16x8*)&As[P][row * 64 + u * 8];                    \
      }                                                                          \
    }                                                                            \
  } while (0)

#define LDB(BF, G, P)                                                            \
  do {                                                                           \
    _Pragma("unroll") for (int fj = 0; fj < 2; fj++) {                           \
      const int row = wn * 64 + (G) * 32 + fj * 16 + fr;                         \
      _Pragma("unroll") for (int kk = 0; kk < 2; kk++) {                         \
        const int u = (kk * 4 + hi) ^ (row & 7);                                 \
        BF[fj][kk] = *(const bf16x8*)&Bs[P][row * 64 + u * 8];                    \
      }                                                                          \
    }                                                                            \
  } while (0)

#define MF(AF, BF, H, G)                                                         \
  do {                                                                           \
    __builtin_amdgcn_s_setprio(1);                                               \
    _Pragma("unroll") for (int fi = 0; fi < 4; fi++)                             \
    _Pragma("unroll") for (int fj = 0; fj < 2; fj++)                             \
    _Pragma("unroll") for (int kk = 0; kk < 2; kk++)                             \
      acc[(H) * 4 + fi][(G) * 2 + fj] = __builtin_amdgcn_mfma_f32_16x16x32_bf16( \
          AF[fi][kk], BF[fj][kk], acc[(H) * 4 + fi][(G) * 2 + fj], 0, 0, 0);     \
    __builtin_amdgcn_s_setprio(0);                                               \
  } while (0)

  const int NT = K >> 6;
  STAGE(0, 0);
  STAGE(1, 1);
  asm volatile("s_waitcnt vmcnt(8)" ::: "memory");
  __builtin_amdgcn_sched_barrier(0);
  GBAR();

  bf16x8 a[4][2], b0[2][2], b1[2][2];
  for (int t = 0; t < NT; t++) {
    const int p = t & 1;
    LDA(a, 0, p);
    LDB(b0, 0, p);
    GBAR(); LGKM0();
    MF(a, b0, 0, 0);
    GBAR();
    LDB(b1, 1, p);
    GBAR(); LGKM0();
    MF(a, b1, 0, 1);
    GBAR();
    LDA(a, 1, p);
    GBAR(); LGKM0();
    MF(a, b0, 1, 0);
    GBAR();
    if (t + 2 < NT) STAGE(t + 2, p);
    GBAR();
    MF(a, b1, 1, 1);
    if (t + 2 < NT) {
      asm volatile("s_waitcnt vmcnt(8)" ::: "memory");
    } else if (t + 1 < NT) {
      asm volatile("s_waitcnt vmcnt(0)" ::: "memory");
    }
    __builtin_amdgcn_sched_barrier(0);
    GBAR();
  }

  if (MODE == 0) {
    const int which = n0 >> 11;
#pragma unroll
    for (int mi = 0; mi < 8; mi++) {
      const int trow = m0 + wm * 128 + mi * 16 + g4;
      const int b = trow >> 11;
      const int t = trow & 2047;
#pragma unroll
      for (int nj = 0; nj < 4; nj++) {
        const int col = n0 + wn * 64 + nj * 16 + fr;
        const int h = (col >> 7) & 15;
        const int dh = col & 127;
        const float bv = bias[col];
        if (which == 2) {
          ushort4 pk;
          pk.x = f2bf(acc[mi][nj][0] + bv);
          pk.y = f2bf(acc[mi][nj][1] + bv);
          pk.z = f2bf(acc[mi][nj][2] + bv);
          pk.w = f2bf(acc[mi][nj][3] + bv);
          *reinterpret_cast<ushort4*>(vtb + ((size_t)(b * NHEADS + h) * DHEAD + dh) * SEQ + t) = pk;
        } else {
          u16* dst = (which == 0) ? qb : kb;
          const float sc = (which == 0) ? 0.08838834764831845f : 1.0f;
#pragma unroll
          for (int r = 0; r < 4; r++)
            dst[((size_t)(b * NHEADS + h) * SEQ + (t + r)) * DHEAD + dh] =
                f2bf((acc[mi][nj][r] + bv) * sc);
        }
      }
    }
  } else {
#pragma unroll
    for (int mi = 0; mi < 8; mi++) {
      const int row = m0 + wm * 128 + mi * 16 + g4;
#pragma unroll
      for (int nj = 0; nj < 4; nj++) {
        const int col = n0 + wn * 64 + nj * 16 + fr;
        const float bv = bias[col];
#pragma unroll
        for (int r = 0; r < 4; r++) outf[(size_t)(row + r) * N + col] = acc[mi][nj][r] + bv;
      }
    }
  }
#undef STAGE
#undef LDA
#undef LDB
#undef MF
}

// Flash attention, non-causal. Q pre-scaled. Grid: (SEQ/128, B*H). 4 waves,
// wave owns 32 Q rows x 128 dh. SWAPPED QK^T: s = mfma(K, Q) so lane (fr,hi)
// holds S[q=fr][k=ct*16+hi*4+r] -> softmax stats per-lane (q=fr), in-lane
// reduce + 2 shfl_xor; P written k-contiguous via ds_write_b64. T13 defer-max.
__global__ __launch_bounds__(256, 2) void attn_fwd(const u16* __restrict__ Q,
                                                   const u16* __restrict__ Kb,
                                                   const u16* __restrict__ VT,
                                                   u16* __restrict__ O) {
  __shared__ __align__(16) u16 Ks[64 * 128];
  __shared__ __align__(16) u16 Vs[128 * 64];
  __shared__ __align__(16) u16 P_lds[4][32][72];
  const int bh = blockIdx.y;
  const int b = bh >> 4, h = bh & 15;
  const int w = threadIdx.x >> 6;
  const int lane = threadIdx.x & 63;
  const int fr = lane & 15;
  const int hi = lane >> 4;
  const int kr = hi * 8;
  const int g4 = hi * 4;
  const int q0w = blockIdx.x * 128 + w * 32;

  const u16* Qp = Q + (size_t)bh * SEQ * DHEAD;
  const u16* Kp = Kb + (size_t)bh * SEQ * DHEAD;
  const u16* Vp = VT + (size_t)bh * DHEAD * SEQ;

  bf16x8 qf[2][4];
#pragma unroll
  for (int mg = 0; mg < 2; mg++)
#pragma unroll
    for (int kk = 0; kk < 4; kk++)
      qf[mg][kk] = *(const bf16x8*)(Qp + (size_t)(q0w + mg * 16 + fr) * DHEAD + kk * 32 + kr);

  f32x4 oacc[2][8];
#pragma unroll
  for (int mg = 0; mg < 2; mg++)
#pragma unroll
    for (int i = 0; i < 8; i++) oacc[mg][i] = f32x4{0.f, 0.f, 0.f, 0.f};
  float mrun[2] = {-1e30f, -1e30f};  // per-lane stats for q = mg*16 + fr
  float lrun[2] = {0.f, 0.f};

  bf16x8 kreg[4], vreg[4];
#pragma unroll
  for (int i = 0; i < 4; i++) {
    const int u = w * 256 + i * 64 + lane;
    const int rK = u >> 4, c16 = u & 15;
    kreg[i] = *(const bf16x8*)(Kp + (size_t)rK * DHEAD + c16 * 8);
    const int rV = u >> 3, c8 = u & 7;
    vreg[i] = *(const bf16x8*)(Vp + (size_t)rV * SEQ + c8 * 8);
  }

  for (int kv0 = 0; kv0 < SEQ; kv0 += 64) {
    __syncthreads();
#pragma unroll
    for (int i = 0; i < 4; i++) {
      const int u = w * 256 + i * 64 + lane;
      const int rK = u >> 4, c16 = u & 15;
      *(bf16x8*)&Ks[rK * 128 + ((c16 ^ (rK & 7)) * 8)] = kreg[i];
      const int rV = u >> 3, c8 = u & 7;
      *(bf16x8*)&Vs[rV * 64 + ((c8 ^ (rV & 7)) * 8)] = vreg[i];
    }
    __syncthreads();
    if (kv0 + 64 < SEQ) {
      const int kvn = kv0 + 64;
#pragma unroll
      for (int i = 0; i < 4; i++) {
        const int u = w * 256 + i * 64 + lane;
        const int rK = u >> 4, c16 = u & 15;
        kreg[i] = *(const bf16x8*)(Kp + (size_t)(kvn + rK) * DHEAD + c16 * 8);
        const int rV = u >> 3, c8 = u & 7;
        vreg[i] = *(const bf16x8*)(Vp + (size_t)rV * SEQ + kvn + c8 * 8);
      }
    }

    // QK^T (swapped): s[mg][ct][r] = S[q = mg*16+fr][k = ct*16 + hi*4 + r]
    f32x4 s[2][4];
#pragma unroll
    for (int mg = 0; mg < 2; mg++)
#pragma unroll
      for (int ct = 0; ct < 4; ct++) s[mg][ct] = f32x4{0.f, 0.f, 0.f, 0.f};
    __builtin_amdgcn_s_setprio(1);
#pragma unroll
    for (int ct = 0; ct < 4; ct++) {
      const int row = ct * 16 + fr;
#pragma unroll
      for (int kk = 0; kk < 4; kk++) {
        bf16x8 kf = *(const bf16x8*)&Ks[row * 128 + (((kk * 4 + hi) ^ (row & 7)) * 8)];
        s[0][ct] = __builtin_amdgcn_mfma_f32_16x16x32_bf16(kf, qf[0][kk], s[0][ct], 0, 0, 0);
        s[1][ct] = __builtin_amdgcn_mfma_f32_16x16x32_bf16(kf, qf[1][kk], s[1][ct], 0, 0, 0);
      }
    }
    __builtin_amdgcn_s_setprio(0);

    // per-lane tile max (16 values) + 2 shfl across hi-group
    float pm[2];
#pragma unroll
    for (int mg = 0; mg < 2; mg++) {
      f32x4 mv = s[mg][0];
      mv[0] = fmaxf(mv[0], s[mg][1][0]); mv[1] = fmaxf(mv[1], s[mg][1][1]);
      mv[2] = fmaxf(mv[2], s[mg][1][2]); mv[3] = fmaxf(mv[3], s[mg][1][3]);
      mv[0] = fmaxf(mv[0], s[mg][2][0]); mv[1] = fmaxf(mv[1], s[mg][2][1]);
      mv[2] = fmaxf(mv[2], s[mg][2][2]); mv[3] = fmaxf(mv[3], s[mg][2][3]);
      mv[0] = fmaxf(mv[0], s[mg][3][0]); mv[1] = fmaxf(mv[1], s[mg][3][1]);
      mv[2] = fmaxf(mv[2], s[mg][3][2]); mv[3] = fmaxf(mv[3], s[mg][3][3]);
      float p = fmaxf(fmaxf(mv[0], mv[1]), fmaxf(mv[2], mv[3]));
      p = fmaxf(p, __shfl_xor(p, 16, 64));
      p = fmaxf(p, __shfl_xor(p, 32, 64));
      pm[mg] = p;
    }

    // T13 defer-max: rescale only if some row grew by > 8
    const bool need = (pm[0] - mrun[0] > 8.f) || (pm[1] - mrun[1] > 8.f);
    if (__any(need)) {
#pragma unroll
      for (int mg = 0; mg < 2; mg++) {
        float nm = fmaxf(mrun[mg], pm[mg]);
        float sfv = __expf(mrun[mg] - nm);
        mrun[mg] = nm;
        lrun[mg] *= sfv;
        float fac[4];
#pragma unroll
        for (int r = 0; r < 4; r++) fac[r] = __shfl(sfv, g4 + r, 64);
#pragma unroll
        for (int dt = 0; dt < 8; dt++) {
          oacc[mg][dt][0] *= fac[0]; oacc[mg][dt][1] *= fac[1];
          oacc[mg][dt][2] *= fac[2]; oacc[mg][dt][3] *= fac[3];
        }
      }
    }

    // exp, row-sum (in-lane + 2 shfl), P -> LDS (k-contiguous b64 writes)
#pragma unroll
    for (int mg = 0; mg < 2; mg++) {
#pragma unroll
      for (int ct = 0; ct < 4; ct++)
#pragma unroll
        for (int r = 0; r < 4; r++) s[mg][ct][r] = __expf(s[mg][ct][r] - mrun[mg]);
      f32x4 sv = s[mg][0] + s[mg][1] + s[mg][2] + s[mg][3];
      float su = (sv[0] + sv[1]) + (sv[2] + sv[3]);
      su += __shfl_xor(su, 16, 64);
      su += __shfl_xor(su, 32, 64);
      lrun[mg] += su;
#pragma unroll
      for (int ct = 0; ct < 4; ct++) {
        ushort4 pk;
        pk.x = f2bf(s[mg][ct][0]); pk.y = f2bf(s[mg][ct][1]);
        pk.z = f2bf(s[mg][ct][2]); pk.w = f2bf(s[mg][ct][3]);
        *reinterpret_cast<ushort4*>(&P_lds[w][mg * 16 + fr][ct * 16 + g4]) = pk;
      }
    }

    // PV (unchanged): A-fragment = P rows q=fr
    bf16x8 pf[2][2];
#pragma unroll
    for (int mg = 0; mg < 2; mg++)
#pragma unroll
      for (int kk = 0; kk < 2; kk++)
        pf[mg][kk] = *(const bf16x8*)&P_lds[w][mg * 16 + fr][kk * 32 + kr];
    __builtin_amdgcn_s_setprio(1);
#pragma unroll
    for (int dt = 0; dt < 8; dt++) {
      const int row = dt * 16 + fr;
#pragma unroll
      for (int kk = 0; kk < 2; kk++) {
        bf16x8 vf = *(const bf16x8*)&Vs[row * 64 + (((kk * 4 + hi) ^ (row & 7)) * 8)];
        oacc[0][dt] = __builtin_amdgcn_mfma_f32_16x16x32_bf16(pf[0][kk], vf, oacc[0][dt], 0, 0, 0);
        oacc[1][dt] = __builtin_amdgcn_mfma_f32_16x16x32_bf16(pf[1][kk], vf, oacc[1][dt], 0, 0, 0);
      }
    }
    __builtin_amdgcn_s_setprio(0);
  }

#pragma unroll
  for (int mg = 0; mg < 2; mg++) {
    float linv = 1.0f / lrun[mg];
    float fac[4];
#pragma unroll
    for (int r = 0; r < 4; r++) fac[r] = __shfl(linv, g4 + r, 64);
#pragma unroll
    for (int r = 0; r < 4; r++) {
      const int t = q0w + mg * 16 + g4 + r;
      u16* op = O + ((size_t)(b * SEQ + t)) * DMODEL + h * DHEAD;
#pragma unroll
      for (int dt = 0; dt < 8; dt++) op[dt * 16 + fr] = f2bf(oacc[mg][dt][r] * fac[r]);
    }
  }
}

extern "C" void kernel_launch(void* const* d_in, const int* in_sizes, int n_in,
                              void* d_out, int out_size, void* d_ws, size_t ws_size,
                              hipStream_t stream) {
  const float* x = (const float*)d_in[0];
  const float* qkv_w = (const float*)d_in[1];
  const float* qkv_b = (const float*)d_in[2];
  const float* out_w = (const float*)d_in[3];
  const float* out_b = (const float*)d_in[4];
  float* out = (float*)d_out;

  char* ws = (char*)d_ws;
  u16* xb = (u16*)ws;
  u16* wqkv = (u16*)(ws + 33554432);
  u16* qb = (u16*)(ws + 33554432 + 25165824);
  u16* kb = qb + (size_t)64 * SEQ * DHEAD;
  u16* vtb = kb + (size_t)64 * SEQ * DHEAD;
  u16* attnb = xb;
  u16* outwb = wqkv;

  cvt_f32_bf16<<<16777216 / 4 / 256, 256, 0, stream>>>(x, xb, 16777216 / 4);
  cvt_f32_bf16<<<12582912 / 4 / 256, 256, 0, stream>>>(qkv_w, wqkv, 12582912 / 4);
  gemm256<0><<<768, 512, 0, stream>>>(xb, wqkv, qkv_b, 8192, 6144, 2048, 24, qb, kb, vtb,
                                      nullptr);
  cvt_f32_bf16<<<4194304 / 4 / 256, 256, 0, stream>>>(out_w, outwb, 4194304 / 4);
  dim3 ga(SEQ / 128, 64);
  attn_fwd<<<ga, 256, 0, stream>>>(qb, kb, vtb, attnb);
  gemm256<1><<<256, 512, 0, stream>>>(attnb, outwb, out_b, 8192, 2048, 2048, 8, nullptr,
                                      nullptr, nullptr, out);
}

// Round 5
// 477.737 us; speedup vs baseline: 2.7786x; 1.0473x over previous
//
#include <hip/hip_runtime.h>

typedef unsigned short u16;
typedef __attribute__((ext_vector_type(8))) __bf16 bf16x8;
typedef __attribute__((ext_vector_type(4))) float f32x4;

#define SEQ 2048
#define DMODEL 2048
#define NHEADS 16
#define DHEAD 128

typedef __attribute__((address_space(1))) void gvoid_t;
typedef __attribute__((address_space(3))) void lvoid_t;

__device__ inline void gload_lds16(const void* g, void* l) {
  __builtin_amdgcn_global_load_lds((gvoid_t*)g, (lvoid_t*)l, 16, 0, 0);
}

__device__ inline u16 f2bf(float f) {
  unsigned u = __float_as_uint(f);
  unsigned r = (u + 0x7fffu + ((u >> 16) & 1u)) >> 16;
  return (u16)r;
}

__global__ __launch_bounds__(256) void cvt_f32_bf16(const float* __restrict__ in,
                                                    u16* __restrict__ out, int n4) {
  int i = blockIdx.x * 256 + threadIdx.x;
  if (i >= n4) return;
  float4 v = reinterpret_cast<const float4*>(in)[i];
  ushort4 o;
  o.x = f2bf(v.x); o.y = f2bf(v.y); o.z = f2bf(v.z); o.w = f2bf(v.w);
  reinterpret_cast<ushort4*>(out)[i] = o;
}

// ---------------- 256x256 GEMM, read-ahead pipelined, constexpr dbuf --------
#define GBAR() __builtin_amdgcn_s_barrier()
#define SB0() __builtin_amdgcn_sched_barrier(0)
#define WAITLGKM(N) do { asm volatile("s_waitcnt lgkmcnt(" #N ")" ::: "memory"); } while (0)
#define WAITVM(N) do { asm volatile("s_waitcnt vmcnt(" #N ")" ::: "memory"); } while (0)

template <int MODE>
__global__ __launch_bounds__(512, 1) void gemm256(
    const u16* __restrict__ A, const u16* __restrict__ B,
    const float* __restrict__ bias, int M, int N, int K, int nby,
    u16* __restrict__ qb, u16* __restrict__ kb, u16* __restrict__ vtb,
    float* __restrict__ outf) {
  __shared__ __align__(16) u16 As[2][256 * 64];
  __shared__ __align__(16) u16 Bs[2][256 * 64];
  const int nwg = gridDim.x;
  const int cpx = nwg >> 3;
  const int bid = blockIdx.x;
  const int sw = (bid & 7) * cpx + (bid >> 3);  // bijective: nwg % 8 == 0
  const int bx = sw / nby, by = sw % nby;
  const int m0 = bx * 256, n0 = by * 256;
  const int tid = threadIdx.x, lane = tid & 63, w = tid >> 6;
  const int wm = w >> 2, wn = w & 3;
  const int fr = lane & 15, hi = lane >> 4;
  const int g4 = hi * 4;
  const u16* Abase = A + (size_t)m0 * K;
  const u16* Bbase = B + (size_t)n0 * K;

  f32x4 acc[8][4];
#pragma unroll
  for (int i = 0; i < 8; i++)
#pragma unroll
    for (int j = 0; j < 4; j++) acc[i][j] = f32x4{0.f, 0.f, 0.f, 0.f};

#define STAGE(T, P)                                                              \
  do {                                                                           \
    const int t64 = (T) * 64;                                                    \
    _Pragma("unroll") for (int j = 0; j < 4; j++) {                              \
      const int U = (j * 8 + w) * 64 + lane;                                     \
      const int r_ = U >> 3;                                                     \
      const int us = (lane & 7) ^ (r_ & 7);                                      \
      gload_lds16(Abase + (size_t)r_ * K + t64 + us * 8, &As[P][U * 8]);         \
      gload_lds16(Bbase + (size_t)r_ * K + t64 + us * 8, &Bs[P][U * 8]);         \
    }                                                                            \
  } while (0)

#define LDA(AF, H, P)                                                            \
  do {                                                                           \
    _Pragma("unroll") for (int fi = 0; fi < 4; fi++) {                           \
      const int row = wm * 128 + (H) * 64 + fi * 16 + fr;                        \
      _Pragma("unroll") for (int kk = 0; kk < 2; kk++) {                         \
        const int u = (kk * 4 + hi) ^ (row & 7);                                 \
        AF[fi][kk] = *(const bf16x8*)&As[P][row * 64 + u * 8];                    \
      }                                                                          \
    }                                                                            \
  } while (0)

#define LDB(BF, G, P)                                                            \
  do {                                                                           \
    _Pragma("unroll") for (int fj = 0; fj < 2; fj++) {                           \
      const int row = wn * 64 + (G) * 32 + fj * 16 + fr;                         \
      _Pragma("unroll") for (int kk = 0; kk < 2; kk++) {                         \
        const int u = (kk * 4 + hi) ^ (row & 7);                                 \
        BF[fj][kk] = *(const bf16x8*)&Bs[P][row * 64 + u * 8];                    \
      }                                                                          \
    }                                                                            \
  } while (0)

#define MF(AF, BF, H, G)                                                         \
  do {                                                                           \
    __builtin_amdgcn_s_setprio(1);                                               \
    _Pragma("unroll") for (int fi = 0; fi < 4; fi++)                             \
    _Pragma("unroll") for (int fj = 0; fj < 2; fj++)                             \
    _Pragma("unroll") for (int kk = 0; kk < 2; kk++)                             \
      acc[(H) * 4 + fi][(G) * 2 + fj] = __builtin_amdgcn_mfma_f32_16x16x32_bf16( \
          AF[fi][kk], BF[fj][kk], acc[(H) * 4 + fi][(G) * 2 + fj], 0, 0, 0);     \
    __builtin_amdgcn_s_setprio(0);                                               \
  } while (0)

// One K-tile, P = constexpr ping-pong index. 3 barriers/tile, counted waits,
// read-ahead: B1 drains under MFMA(00); A-half1 reads issue after quadrant
// (0,1) MFMAs (anti-dep ordered) and drain under the CU's MFMA backlog.
#define TILE(T, P)                                                               \
  do {                                                                           \
    LDA(a, 0, P); SB0();                                                         \
    LDB(b0, 0, P); SB0();                                                        \
    LDB(b1, 1, P); SB0();                                                        \
    GBAR(); SB0();                                                               \
    WAITLGKM(4); SB0();                                                          \
    MF(a, b0, 0, 0);                                                             \
    WAITLGKM(0); SB0();                                                          \
    MF(a, b1, 0, 1);                                                             \
    LDA(a, 1, P); SB0();                                                         \
    WAITLGKM(0); SB0();                                                          \
    GBAR(); SB0();                                                               \
    if ((T) + 2 < NT) STAGE((T) + 2, P);                                         \
    SB0();                                                                       \
    MF(a, b0, 1, 0);                                                             \
    MF(a, b1, 1, 1);                                                             \
    if ((T) + 2 < NT) { WAITVM(8); }                                             \
    else if ((T) + 1 < NT) { WAITVM(0); }                                        \
    SB0();                                                                       \
    GBAR(); SB0();                                                               \
  } while (0)

  const int NT = K >> 6;  // even (K = 2048 -> 32)
  STAGE(0, 0);
  STAGE(1, 1);
  WAITVM(8); SB0();
  GBAR(); SB0();

  bf16x8 a[4][2], b0[2][2], b1[2][2];
  for (int t = 0; t + 1 < NT; t += 2) {
    TILE(t, 0);
    TILE(t + 1, 1);
  }

  if (MODE == 0) {
    const int which = n0 >> 11;
#pragma unroll
    for (int mi = 0; mi < 8; mi++) {
      const int trow = m0 + wm * 128 + mi * 16 + g4;
      const int b = trow >> 11;
      const int t = trow & 2047;
#pragma unroll
      for (int nj = 0; nj < 4; nj++) {
        const int col = n0 + wn * 64 + nj * 16 + fr;
        const int h = (col >> 7) & 15;
        const int dh = col & 127;
        const float bv = bias[col];
        if (which == 2) {
          ushort4 pk;
          pk.x = f2bf(acc[mi][nj][0] + bv);
          pk.y = f2bf(acc[mi][nj][1] + bv);
          pk.z = f2bf(acc[mi][nj][2] + bv);
          pk.w = f2bf(acc[mi][nj][3] + bv);
          *reinterpret_cast<ushort4*>(vtb + ((size_t)(b * NHEADS + h) * DHEAD + dh) * SEQ + t) = pk;
        } else {
          u16* dst = (which == 0) ? qb : kb;
          const float sc = (which == 0) ? 0.08838834764831845f : 1.0f;
#pragma unroll
          for (int r = 0; r < 4; r++)
            dst[((size_t)(b * NHEADS + h) * SEQ + (t + r)) * DHEAD + dh] =
                f2bf((acc[mi][nj][r] + bv) * sc);
        }
      }
    }
  } else {
#pragma unroll
    for (int mi = 0; mi < 8; mi++) {
      const int row = m0 + wm * 128 + mi * 16 + g4;
#pragma unroll
      for (int nj = 0; nj < 4; nj++) {
        const int col = n0 + wn * 64 + nj * 16 + fr;
        const float bv = bias[col];
#pragma unroll
        for (int r = 0; r < 4; r++) outf[(size_t)(row + r) * N + col] = acc[mi][nj][r] + bv;
      }
    }
  }
#undef STAGE
#undef LDA
#undef LDB
#undef MF
#undef TILE
}

// Flash attention, non-causal. Q pre-scaled. Grid: (SEQ/128, B*H). 4 waves,
// wave owns 32 Q rows x 128 dh. SWAPPED QK^T: s = mfma(K, Q) so lane (fr,hi)
// holds S[q=fr][k=ct*16+hi*4+r] -> softmax stats per-lane (q=fr), in-lane
// reduce + 2 shfl_xor; P written k-contiguous via ds_write_b64. T13 defer-max.
__global__ __launch_bounds__(256, 2) void attn_fwd(const u16* __restrict__ Q,
                                                   const u16* __restrict__ Kb,
                                                   const u16* __restrict__ VT,
                                                   u16* __restrict__ O) {
  __shared__ __align__(16) u16 Ks[64 * 128];
  __shared__ __align__(16) u16 Vs[128 * 64];
  __shared__ __align__(16) u16 P_lds[4][32][72];
  const int bh = blockIdx.y;
  const int b = bh >> 4, h = bh & 15;
  const int w = threadIdx.x >> 6;
  const int lane = threadIdx.x & 63;
  const int fr = lane & 15;
  const int hi = lane >> 4;
  const int kr = hi * 8;
  const int g4 = hi * 4;
  const int q0w = blockIdx.x * 128 + w * 32;

  const u16* Qp = Q + (size_t)bh * SEQ * DHEAD;
  const u16* Kp = Kb + (size_t)bh * SEQ * DHEAD;
  const u16* Vp = VT + (size_t)bh * DHEAD * SEQ;

  bf16x8 qf[2][4];
#pragma unroll
  for (int mg = 0; mg < 2; mg++)
#pragma unroll
    for (int kk = 0; kk < 4; kk++)
      qf[mg][kk] = *(const bf16x8*)(Qp + (size_t)(q0w + mg * 16 + fr) * DHEAD + kk * 32 + kr);

  f32x4 oacc[2][8];
#pragma unroll
  for (int mg = 0; mg < 2; mg++)
#pragma unroll
    for (int i = 0; i < 8; i++) oacc[mg][i] = f32x4{0.f, 0.f, 0.f, 0.f};
  float mrun[2] = {-1e30f, -1e30f};  // per-lane stats for q = mg*16 + fr
  float lrun[2] = {0.f, 0.f};

  bf16x8 kreg[4], vreg[4];
#pragma unroll
  for (int i = 0; i < 4; i++) {
    const int u = w * 256 + i * 64 + lane;
    const int rK = u >> 4, c16 = u & 15;
    kreg[i] = *(const bf16x8*)(Kp + (size_t)rK * DHEAD + c16 * 8);
    const int rV = u >> 3, c8 = u & 7;
    vreg[i] = *(const bf16x8*)(Vp + (size_t)rV * SEQ + c8 * 8);
  }

  for (int kv0 = 0; kv0 < SEQ; kv0 += 64) {
    __syncthreads();
#pragma unroll
    for (int i = 0; i < 4; i++) {
      const int u = w * 256 + i * 64 + lane;
      const int rK = u >> 4, c16 = u & 15;
      *(bf16x8*)&Ks[rK * 128 + ((c16 ^ (rK & 7)) * 8)] = kreg[i];
      const int rV = u >> 3, c8 = u & 7;
      *(bf16x8*)&Vs[rV * 64 + ((c8 ^ (rV & 7)) * 8)] = vreg[i];
    }
    __syncthreads();
    if (kv0 + 64 < SEQ) {
      const int kvn = kv0 + 64;
#pragma unroll
      for (int i = 0; i < 4; i++) {
        const int u = w * 256 + i * 64 + lane;
        const int rK = u >> 4, c16 = u & 15;
        kreg[i] = *(const bf16x8*)(Kp + (size_t)(kvn + rK) * DHEAD + c16 * 8);
        const int rV = u >> 3, c8 = u & 7;
        vreg[i] = *(const bf16x8*)(Vp + (size_t)rV * SEQ + kvn + c8 * 8);
      }
    }

    // QK^T (swapped): s[mg][ct][r] = S[q = mg*16+fr][k = ct*16 + hi*4 + r]
    f32x4 s[2][4];
#pragma unroll
    for (int mg = 0; mg < 2; mg++)
#pragma unroll
      for (int ct = 0; ct < 4; ct++) s[mg][ct] = f32x4{0.f, 0.f, 0.f, 0.f};
    __builtin_amdgcn_s_setprio(1);
#pragma unroll
    for (int ct = 0; ct < 4; ct++) {
      const int row = ct * 16 + fr;
#pragma unroll
      for (int kk = 0; kk < 4; kk++) {
        bf16x8 kf = *(const bf16x8*)&Ks[row * 128 + (((kk * 4 + hi) ^ (row & 7)) * 8)];
        s[0][ct] = __builtin_amdgcn_mfma_f32_16x16x32_bf16(kf, qf[0][kk], s[0][ct], 0, 0, 0);
        s[1][ct] = __builtin_amdgcn_mfma_f32_16x16x32_bf16(kf, qf[1][kk], s[1][ct], 0, 0, 0);
      }
    }
    __builtin_amdgcn_s_setprio(0);

    // per-lane tile max (16 values) + 2 shfl across hi-group
    float pm[2];
#pragma unroll
    for (int mg = 0; mg < 2; mg++) {
      f32x4 mv = s[mg][0];
      mv[0] = fmaxf(mv[0], s[mg][1][0]); mv[1] = fmaxf(mv[1], s[mg][1][1]);
      mv[2] = fmaxf(mv[2], s[mg][1][2]); mv[3] = fmaxf(mv[3], s[mg][1][3]);
      mv[0] = fmaxf(mv[0], s[mg][2][0]); mv[1] = fmaxf(mv[1], s[mg][2][1]);
      mv[2] = fmaxf(mv[2], s[mg][2][2]); mv[3] = fmaxf(mv[3], s[mg][2][3]);
      mv[0] = fmaxf(mv[0], s[mg][3][0]); mv[1] = fmaxf(mv[1], s[mg][3][1]);
      mv[2] = fmaxf(mv[2], s[mg][3][2]); mv[3] = fmaxf(mv[3], s[mg][3][3]);
      float p = fmaxf(fmaxf(mv[0], mv[1]), fmaxf(mv[2], mv[3]));
      p = fmaxf(p, __shfl_xor(p, 16, 64));
      p = fmaxf(p, __shfl_xor(p, 32, 64));
      pm[mg] = p;
    }

    // T13 defer-max: rescale only if some row grew by > 8
    const bool need = (pm[0] - mrun[0] > 8.f) || (pm[1] - mrun[1] > 8.f);
    if (__any(need)) {
#pragma unroll
      for (int mg = 0; mg < 2; mg++) {
        float nm = fmaxf(mrun[mg], pm[mg]);
        float sfv = __expf(mrun[mg] - nm);
        mrun[mg] = nm;
        lrun[mg] *= sfv;
        float fac[4];
#pragma unroll
        for (int r = 0; r < 4; r++) fac[r] = __shfl(sfv, g4 + r, 64);
#pragma unroll
        for (int dt = 0; dt < 8; dt++) {
          oacc[mg][dt][0] *= fac[0]; oacc[mg][dt][1] *= fac[1];
          oacc[mg][dt][2] *= fac[2]; oacc[mg][dt][3] *= fac[3];
        }
      }
    }

    // exp, row-sum (in-lane + 2 shfl), P -> LDS (k-contiguous b64 writes)
#pragma unroll
    for (int mg = 0; mg < 2; mg++) {
#pragma unroll
      for (int ct = 0; ct < 4; ct++)
#pragma unroll
        for (int r = 0; r < 4; r++) s[mg][ct][r] = __expf(s[mg][ct][r] - mrun[mg]);
      f32x4 sv = s[mg][0] + s[mg][1] + s[mg][2] + s[mg][3];
      float su = (sv[0] + sv[1]) + (sv[2] + sv[3]);
      su += __shfl_xor(su, 16, 64);
      su += __shfl_xor(su, 32, 64);
      lrun[mg] += su;
#pragma unroll
      for (int ct = 0; ct < 4; ct++) {
        ushort4 pk;
        pk.x = f2bf(s[mg][ct][0]); pk.y = f2bf(s[mg][ct][1]);
        pk.z = f2bf(s[mg][ct][2]); pk.w = f2bf(s[mg][ct][3]);
        *reinterpret_cast<ushort4*>(&P_lds[w][mg * 16 + fr][ct * 16 + g4]) = pk;
      }
    }

    // PV (unchanged): A-fragment = P rows q=fr
    bf16x8 pf[2][2];
#pragma unroll
    for (int mg = 0; mg < 2; mg++)
#pragma unroll
      for (int kk = 0; kk < 2; kk++)
        pf[mg][kk] = *(const bf16x8*)&P_lds[w][mg * 16 + fr][kk * 32 + kr];
    __builtin_amdgcn_s_setprio(1);
#pragma unroll
    for (int dt = 0; dt < 8; dt++) {
      const int row = dt * 16 + fr;
#pragma unroll
      for (int kk = 0; kk < 2; kk++) {
        bf16x8 vf = *(const bf16x8*)&Vs[row * 64 + (((kk * 4 + hi) ^ (row & 7)) * 8)];
        oacc[0][dt] = __builtin_amdgcn_mfma_f32_16x16x32_bf16(pf[0][kk], vf, oacc[0][dt], 0, 0, 0);
        oacc[1][dt] = __builtin_amdgcn_mfma_f32_16x16x32_bf16(pf[1][kk], vf, oacc[1][dt], 0, 0, 0);
      }
    }
    __builtin_amdgcn_s_setprio(0);
  }

#pragma unroll
  for (int mg = 0; mg < 2; mg++) {
    float linv = 1.0f / lrun[mg];
    float fac[4];
#pragma unroll
    for (int r = 0; r < 4; r++) fac[r] = __shfl(linv, g4 + r, 64);
#pragma unroll
    for (int r = 0; r < 4; r++) {
      const int t = q0w + mg * 16 + g4 + r;
      u16* op = O + ((size_t)(b * SEQ + t)) * DMODEL + h * DHEAD;
#pragma unroll
      for (int dt = 0; dt < 8; dt++) op[dt * 16 + fr] = f2bf(oacc[mg][dt][r] * fac[r]);
    }
  }
}

extern "C" void kernel_launch(void* const* d_in, const int* in_sizes, int n_in,
                              void* d_out, int out_size, void* d_ws, size_t ws_size,
                              hipStream_t stream) {
  const float* x = (const float*)d_in[0];
  const float* qkv_w = (const float*)d_in[1];
  const float* qkv_b = (const float*)d_in[2];
  const float* out_w = (const float*)d_in[3];
  const float* out_b = (const float*)d_in[4];
  float* out = (float*)d_out;

  char* ws = (char*)d_ws;
  u16* xb = (u16*)ws;
  u16* wqkv = (u16*)(ws + 33554432);
  u16* qb = (u16*)(ws + 33554432 + 25165824);
  u16* kb = qb + (size_t)64 * SEQ * DHEAD;
  u16* vtb = kb + (size_t)64 * SEQ * DHEAD;
  u16* attnb = xb;
  u16* outwb = wqkv;

  cvt_f32_bf16<<<16777216 / 4 / 256, 256, 0, stream>>>(x, xb, 16777216 / 4);
  cvt_f32_bf16<<<12582912 / 4 / 256, 256, 0, stream>>>(qkv_w, wqkv, 12582912 / 4);
  gemm256<0><<<768, 512, 0, stream>>>(xb, wqkv, qkv_b, 8192, 6144, 2048, 24, qb, kb, vtb,
                                      nullptr);
  cvt_f32_bf16<<<4194304 / 4 / 256, 256, 0, stream>>>(out_w, outwb, 4194304 / 4);
  dim3 ga(SEQ / 128, 64);
  attn_fwd<<<ga, 256, 0, stream>>>(qb, kb, vtb, attnb);
  gemm256<1><<<256, 512, 0, stream>>>(attnb, outwb, out_b, 8192, 2048, 2048, 8, nullptr,
                                      nullptr, nullptr, out);
}